// Round 9
// baseline (166.390 us; speedup 1.0000x reference)
//
#include <hip/hip_runtime.h>
#include <hip/hip_bf16.h>
#include <math.h>

// Problem constants: B=32 V=512 K=16 D=128 E=32 NE=8192 -> BV=16384 vertices
#define NLSTR 136   // LDS row stride (ushorts) for 16x128 tiles

typedef __bf16 bf16x8 __attribute__((ext_vector_type(8)));
typedef float f32x4 __attribute__((ext_vector_type(4)));
typedef float f32x16 __attribute__((ext_vector_type(16)));
typedef unsigned short ushort8v __attribute__((ext_vector_type(8)));

union FragU { ushort8v u; bf16x8 b; };

static __device__ inline unsigned short f2bf(float f){
  unsigned u = __float_as_uint(f);
  u += 0x7fffu + ((u >> 16) & 1u);   // RNE
  return (unsigned short)(u >> 16);
}
static __device__ inline float bf2f(unsigned short u){
  return __uint_as_float(((unsigned)u) << 16);
}
static __device__ inline unsigned pk2(float a, float b){
  union { __hip_bfloat162 h; unsigned u; } r;
  r.h = __float22bfloat162_rn(float2{a, b});
  return r.u;
}
static __device__ inline ushort8v pkcvt8(float4 a, float4 b){
  union { unsigned u[4]; ushort8v v; } r;
  r.u[0] = pk2(a.x, a.y); r.u[1] = pk2(a.z, a.w);
  r.u[2] = pk2(b.x, b.y); r.u[3] = pk2(b.z, b.w);
  return r.v;
}

// tanh-form GELU (max err ~3e-4 vs exact erf-GELU)
static __device__ inline float gelu_f(float x){
  float u = x * x;
  float p = fmaf(u, 0.07135481283f, 1.5957691216f);
  float t = x * p;
  float e = __builtin_amdgcn_exp2f(t * -1.44269504f);
  return x * __builtin_amdgcn_rcpf(1.0f + e);
}

// ---------------- prep: bf16 vertex table + fragment-order bf16 weights ----------------
// w1f: 32x32x16 B-frags, STRIP-MAJOR: frag (nc2*10+kc), elem j of lane:
//      W1[(nc2*32+(lane&31))*160 + kc*16 + (lane>>5)*8 + j]
// w2f/w3f: 16x16x32 B-frags: frag (kc*8+nc), elem j: W[(nc*16+col)*rowlen + kc*32 + quad*8 + j]
__global__ __launch_bounds__(256) void prep_kernel(
    const float* __restrict__ vf, const float* __restrict__ W1,
    const float* __restrict__ W2, const float* __restrict__ W3,
    unsigned short* __restrict__ vfbf, unsigned short* __restrict__ w1f,
    unsigned short* __restrict__ w2f, unsigned short* __restrict__ w3f)
{
  int t = blockIdx.x * 256 + threadIdx.x;
  if (t < 262144){                       // 16384*128 / 8
    const float4* src = (const float4*)vf;
    float4 x = src[t * 2], y = src[t * 2 + 1];
    *(ushort8v*)(vfbf + t * 8) = pkcvt8(x, y);
    return;
  }
  int t2 = t - 262144;
  const float* s;
  unsigned short* d;
  if (t2 < 2560){                        // w1f: 4nc2 x 10kc strip-major (32x32x16)
    int fragid = t2 >> 6, lane = t2 & 63;
    int nc2 = fragid / 10, kc = fragid % 10, n = lane & 31, h = lane >> 5;
    s = W1 + (nc2 * 32 + n) * 160 + kc * 16 + h * 8;
    d = w1f + t2 * 8;
  } else if (t2 < 6656){                 // w2f: 8kc x 8nc
    int t3 = t2 - 2560;
    int fragid = t3 >> 6, lane = t3 & 63;
    int kc = fragid >> 3, nc = fragid & 7, col = lane & 15, quad = lane >> 4;
    s = W2 + (nc * 16 + col) * 256 + kc * 32 + quad * 8;
    d = w2f + t3 * 8;
  } else if (t2 < 8704){                 // w3f: 4kc x 8nc
    int t3 = t2 - 6656;
    int fragid = t3 >> 6, lane = t3 & 63;
    int kc = fragid >> 3, nc = fragid & 7, col = lane & 15, quad = lane >> 4;
    s = W3 + (nc * 16 + col) * 128 + kc * 32 + quad * 8;
    d = w3f + t3 * 8;
  } else return;
#pragma unroll
  for (int j = 0; j < 8; j++) d[j] = f2bf(s[j]);
}

// ---------------- fused ----------------
// grid 1024 x 256thr. Block = 16 vertices = 8 pairs. Stage1 is BARRIER-FREE:
// wave wid owns output cols [wid*32,+32) with its 10 W1 B-frags resident in 40
// VGPRs (zero B traffic), and gathers its OWN A-fragments directly in 32x32
// A-layout (lane n32 = row m -> no LDS round-trip, no cross-wave coupling; 4x
// redundant gathers are L2/L3-served). Double-buffered prefetch, edge kept raw
// fp32 until use (issue not vmcnt-blocked). Compiler free to use vmcnt(N).
__global__ __launch_bounds__(256, 1) void fused_kernel(
    const unsigned short* __restrict__ vfbf,
    const int* __restrict__ aadj, const int* __restrict__ badj,
    const float* __restrict__ edge, const float* __restrict__ nbs,
    const float* __restrict__ h0,
    const unsigned short* __restrict__ w1f, const unsigned short* __restrict__ w2f,
    const unsigned short* __restrict__ w3f,
    const float* __restrict__ b1, const float* __restrict__ b2, const float* __restrict__ b3,
    const float* __restrict__ lamda, const float* __restrict__ alpha,
    const int* __restrict__ lval,
    float* __restrict__ out)
{
  __shared__ __align__(16) unsigned short nl_lds[16 * NLSTR];
  __shared__ __align__(16) unsigned short sup_lds[16 * NLSTR];
  const int wid  = threadIdx.x >> 6;
  const int lane = threadIdx.x & 63;
  const int n32  = lane & 31;          // A row m / output col within chunk
  const int h    = lane >> 5;          // k-half selector
  const int col  = lane & 15;          // stage2
  const int quad = lane >> 4;          // stage2
  const int v0   = blockIdx.x * 16;

  // ---- B strip into registers (wave wid -> nc2 = wid): 10 frags = 40 VGPR ----
  FragU bw[10];
#pragma unroll
  for (int kc = 0; kc < 10; kc++)
    bw[kc].u = *(const ushort8v*)(w1f + ((wid * 10 + kc) * 64 + lane) * 8);

  const float bb1 = b1[wid * 32 + n32];
  const float4* nbs4 = (const float4*)(nbs);

  // ---- per-lane adjacency: lane row n32 of pair p -> flat index v0*16 + 32p + n32 ----
  int a_[8], e_[8];
  {
    const int base = v0 * 16 + n32;
#pragma unroll
    for (int p = 0; p < 8; p++){
      a_[p] = aadj[base + 32 * p];
      e_[p] = badj[base + 32 * p];
    }
  }

  // double-buffered prefetch state (regs; constant indices under full unroll)
  ushort8v pav[2][8];
  float4   pe[2][4];

  // prologue: issue pair-0 gathers
  {
    const unsigned short* vr = vfbf + (size_t)a_[0] * 128 + h * 8;
#pragma unroll
    for (int kc = 0; kc < 8; kc++) pav[0][kc] = *(const ushort8v*)(vr + kc * 16);
    const float* er = edge + (size_t)e_[0] * 32 + h * 8;
    pe[0][0] = *(const float4*)(er);      pe[0][1] = *(const float4*)(er + 4);
    pe[0][2] = *(const float4*)(er + 16); pe[0][3] = *(const float4*)(er + 20);
  }

#pragma unroll
  for (int p = 0; p < 8; ++p){
    const int cur = p & 1, nxt = cur ^ 1;
    // ---- issue pair p+1 gathers (consumed next iteration; no barrier anywhere) ----
    if (p < 7){
      const unsigned short* vr = vfbf + (size_t)a_[p + 1] * 128 + h * 8;
#pragma unroll
      for (int kc = 0; kc < 8; kc++) pav[nxt][kc] = *(const ushort8v*)(vr + kc * 16);
      const float* er = edge + (size_t)e_[p + 1] * 32 + h * 8;
      pe[nxt][0] = *(const float4*)(er);      pe[nxt][1] = *(const float4*)(er + 4);
      pe[nxt][2] = *(const float4*)(er + 16); pe[nxt][3] = *(const float4*)(er + 20);
    }

    // ---- masks for pair p (L2-resident; issued before MFMA to cover latency) ----
    const int vA = v0 + 2 * p;
    const float4 mAlo = nbs4[vA * 4 + h],       mAhi = nbs4[vA * 4 + 2 + h];
    const float4 mBlo = nbs4[(vA + 1) * 4 + h], mBhi = nbs4[(vA + 1) * 4 + 2 + h];

    // ---- pair-p MFMA: A + B both in registers ----
    FragU ef0, ef1;
    ef0.u = pkcvt8(pe[cur][0], pe[cur][1]);   // kc=8 (loads are one full iteration old)
    ef1.u = pkcvt8(pe[cur][2], pe[cur][3]);   // kc=9
    f32x16 acc = {};
#pragma unroll
    for (int kc = 0; kc < 8; kc++){
      FragU fa; fa.u = pav[cur][kc];
      acc = __builtin_amdgcn_mfma_f32_32x32x16_bf16(fa.b, bw[kc].b, acc, 0, 0, 0);
    }
    acc = __builtin_amdgcn_mfma_f32_32x32x16_bf16(ef0.b, bw[8].b, acc, 0, 0, 0);
    acc = __builtin_amdgcn_mfma_f32_32x32x16_bf16(ef1.b, bw[9].b, acc, 0, 0, 0);

    // ---- epilogue: +b1, GELU, mask, reduce; C row=(reg&3)+8*(reg>>2)+4*h ----
    {
      float sA = gelu_f(acc[0] + bb1) * mAlo.x + gelu_f(acc[1] + bb1) * mAlo.y
               + gelu_f(acc[2] + bb1) * mAlo.z + gelu_f(acc[3] + bb1) * mAlo.w
               + gelu_f(acc[4] + bb1) * mAhi.x + gelu_f(acc[5] + bb1) * mAhi.y
               + gelu_f(acc[6] + bb1) * mAhi.z + gelu_f(acc[7] + bb1) * mAhi.w;
      float sB = gelu_f(acc[8] + bb1) * mBlo.x + gelu_f(acc[9] + bb1) * mBlo.y
               + gelu_f(acc[10] + bb1) * mBlo.z + gelu_f(acc[11] + bb1) * mBlo.w
               + gelu_f(acc[12] + bb1) * mBhi.x + gelu_f(acc[13] + bb1) * mBhi.y
               + gelu_f(acc[14] + bb1) * mBhi.z + gelu_f(acc[15] + bb1) * mBhi.w;
      sA += __shfl_xor(sA, 32, 64);
      sB += __shfl_xor(sB, 32, 64);
      if (h == 0) nl_lds[(2 * p)     * NLSTR + wid * 32 + n32] = f2bf(sA);
      else        nl_lds[(2 * p + 1) * NLSTR + wid * 32 + n32] = f2bf(sB);
    }
  }
  __syncthreads();

  // ---------------- stage 2: wave wid computes output cols [wid*32, wid*32+32) --------
  const int nc0 = 2 * wid;
  const float th = logf(lamda[0] / (float)lval[0] + 1.0f);
  const float al = alpha[0];

  f32x4 acc2[2] = {};
#pragma unroll
  for (int kc = 0; kc < 8; kc++){
    FragU a;
    if (kc < 4) a.u = *(const ushort8v*)(nl_lds + col * NLSTR + kc * 32 + quad * 8);
    else        a.u = *(const ushort8v*)(vfbf + (size_t)(v0 + col) * 128 + (kc - 4) * 32 + quad * 8);
#pragma unroll
    for (int pq = 0; pq < 2; pq++){
      FragU bf_;
      bf_.u = *(const ushort8v*)(w2f + ((kc * 8 + nc0 + pq) * 64 + lane) * 8);
      acc2[pq] = __builtin_amdgcn_mfma_f32_16x16x32_bf16(a.b, bf_.b, acc2[pq], 0, 0, 0);
    }
  }

  float sup[2][4];
#pragma unroll
  for (int pq = 0; pq < 2; pq++){
    const int d = (nc0 + pq) * 16 + col;
    const float bb = b2[d];
#pragma unroll
    for (int r = 0; r < 4; r++){
      const int vtx = v0 + quad * 4 + r;
      float hi = acc2[pq][r] + bb;
      float s = (1.f - al) * hi + al * h0[vtx * 128 + d];
      sup[pq][r] = s;
      sup_lds[(quad * 4 + r) * NLSTR + d] = f2bf(s);
    }
  }
  __syncthreads();

  f32x4 acc3[2] = {};
#pragma unroll
  for (int kc = 0; kc < 4; kc++){
    FragU a;
    a.u = *(const ushort8v*)(sup_lds + col * NLSTR + kc * 32 + quad * 8);
#pragma unroll
    for (int pq = 0; pq < 2; pq++){
      FragU bf_;
      bf_.u = *(const ushort8v*)(w3f + ((kc * 8 + nc0 + pq) * 64 + lane) * 8);
      acc3[pq] = __builtin_amdgcn_mfma_f32_16x16x32_bf16(a.b, bf_.b, acc3[pq], 0, 0, 0);
    }
  }

#pragma unroll
  for (int pq = 0; pq < 2; pq++){
    const int d = (nc0 + pq) * 16 + col;
    const float bb = b3[d];
#pragma unroll
    for (int r = 0; r < 4; r++){
      const int vtx = v0 + quad * 4 + r;
      float res = bf2f(vfbf[(size_t)vtx * 128 + d]);
      out[vtx * 128 + d] = th * (acc3[pq][r] + bb) + (1.f - th) * sup[pq][r] + res;
    }
  }
}

extern "C" void kernel_launch(void* const* d_in, const int* in_sizes, int n_in,
                              void* d_out, int out_size, void* d_ws, size_t ws_size,
                              hipStream_t stream)
{
  const float* vfp  = (const float*)d_in[0];
  const int*   aadj = (const int*)d_in[1];
  const int*   badj = (const int*)d_in[2];
  const float* h0   = (const float*)d_in[3];
  const float* lam  = (const float*)d_in[4];
  const float* alp  = (const float*)d_in[5];
  const int*   lv   = (const int*)d_in[6];
  const float* edge = (const float*)d_in[7];
  // d_in[8] vertex_mask: unused by the reference math
  const float* nbs  = (const float*)d_in[9];
  const float* W1   = (const float*)d_in[10];
  const float* b1   = (const float*)d_in[11];
  const float* W2   = (const float*)d_in[12];
  const float* b2   = (const float*)d_in[13];
  const float* W3   = (const float*)d_in[14];
  const float* b3   = (const float*)d_in[15];
  float* out = (float*)d_out;

  // ws layout (ushorts): w1f [0,20480) | w2f [20480,53248) | w3f [53248,69632)
  //                      | vfbf [69632, 69632+2097152)
  unsigned short* w1f  = (unsigned short*)d_ws;
  unsigned short* w2f  = w1f + 20480;
  unsigned short* w3f  = w2f + 32768;
  unsigned short* vfbf = w3f + 16384;

  prep_kernel<<<1058, 256, 0, stream>>>(vfp, W1, W2, W3, vfbf, w1f, w2f, w3f);
  fused_kernel<<<1024, 256, 0, stream>>>(vfbf, aadj, badj, edge, nbs, h0,
                                         w1f, w2f, w3f, b1, b2, b3, lam, alp, lv, out);
}

// Round 10
// 146.189 us; speedup vs baseline: 1.1382x; 1.1382x over previous
//
#include <hip/hip_runtime.h>
#include <hip/hip_bf16.h>
#include <math.h>

// Problem constants: B=32 V=512 K=16 D=128 E=32 NE=8192 -> BV=16384 vertices
#define NLSTR 136   // LDS row stride (ushorts) for 16x128 tiles
#define ASTR  168   // LDS row stride (ushorts) for A rows: 160 + 8 pad (336B, 16B-aligned)

typedef __bf16 bf16x8 __attribute__((ext_vector_type(8)));
typedef float f32x4 __attribute__((ext_vector_type(4)));
typedef float f32x16 __attribute__((ext_vector_type(16)));
typedef unsigned short ushort8v __attribute__((ext_vector_type(8)));

union FragU { ushort8v u; bf16x8 b; };

static __device__ inline unsigned short f2bf(float f){
  unsigned u = __float_as_uint(f);
  u += 0x7fffu + ((u >> 16) & 1u);   // RNE
  return (unsigned short)(u >> 16);
}
static __device__ inline float bf2f(unsigned short u){
  return __uint_as_float(((unsigned)u) << 16);
}
static __device__ inline unsigned pk2(float a, float b){
  union { __hip_bfloat162 h; unsigned u; } r;
  r.h = __float22bfloat162_rn(float2{a, b});
  return r.u;
}
static __device__ inline ushort8v pkcvt8(float4 a, float4 b){
  union { unsigned u[4]; ushort8v v; } r;
  r.u[0] = pk2(a.x, a.y); r.u[1] = pk2(a.z, a.w);
  r.u[2] = pk2(b.x, b.y); r.u[3] = pk2(b.z, b.w);
  return r.v;
}

// tanh-form GELU (max err ~3e-4 vs exact erf-GELU)
static __device__ inline float gelu_f(float x){
  float u = x * x;
  float p = fmaf(u, 0.07135481283f, 1.5957691216f);
  float t = x * p;
  float e = __builtin_amdgcn_exp2f(t * -1.44269504f);
  return x * __builtin_amdgcn_rcpf(1.0f + e);
}

// ---------------- prep: bf16 edge + vertex tables + fragment-order bf16 weights --------
// ebf: edge table cast to bf16 (16 MB) -- halves fused's random-gather HBM bytes.
// w1f: 32x32x16 B-frags, strip-major (nc2*10+kc);  w2f/w3f: 16x16x32 B-frags (kc*8+nc).
__global__ __launch_bounds__(256) void prep_kernel(
    const float* __restrict__ vf, const float* __restrict__ edge,
    const float* __restrict__ W1, const float* __restrict__ W2, const float* __restrict__ W3,
    unsigned short* __restrict__ vfbf, unsigned short* __restrict__ ebf,
    unsigned short* __restrict__ w1f, unsigned short* __restrict__ w2f,
    unsigned short* __restrict__ w3f)
{
  int t = blockIdx.x * 256 + threadIdx.x;
  if (t < 1048576){                      // edge: 262144*32 floats / 8 per thread
    const float4* src = (const float4*)edge;
    float4 x = src[t * 2], y = src[t * 2 + 1];
    *(ushort8v*)(ebf + (size_t)t * 8) = pkcvt8(x, y);
    return;
  }
  t -= 1048576;
  if (t < 262144){                       // vfbf: 16384*128 / 8
    const float4* src = (const float4*)vf;
    float4 x = src[t * 2], y = src[t * 2 + 1];
    *(ushort8v*)(vfbf + (size_t)t * 8) = pkcvt8(x, y);
    return;
  }
  int t2 = t - 262144;
  const float* s;
  unsigned short* d;
  if (t2 < 2560){                        // w1f: 4nc2 x 10kc strip-major (32x32x16)
    int fragid = t2 >> 6, lane = t2 & 63;
    int nc2 = fragid / 10, kc = fragid % 10, n = lane & 31, h = lane >> 5;
    s = W1 + (nc2 * 32 + n) * 160 + kc * 16 + h * 8;
    d = w1f + t2 * 8;
  } else if (t2 < 6656){                 // w2f: 8kc x 8nc
    int t3 = t2 - 2560;
    int fragid = t3 >> 6, lane = t3 & 63;
    int kc = fragid >> 3, nc = fragid & 7, col = lane & 15, quad = lane >> 4;
    s = W2 + (nc * 16 + col) * 256 + kc * 32 + quad * 8;
    d = w2f + t3 * 8;
  } else if (t2 < 8704){                 // w3f: 4kc x 8nc
    int t3 = t2 - 6656;
    int fragid = t3 >> 6, lane = t3 & 63;
    int kc = fragid >> 3, nc = fragid & 7, col = lane & 15, quad = lane >> 4;
    s = W3 + (nc * 16 + col) * 128 + kc * 32 + quad * 8;
    d = w3f + t3 * 8;
  } else return;
#pragma unroll
  for (int j = 0; j < 8; j++) d[j] = f2bf(s[j]);
}

// ---------------- fused ----------------
// grid 1024 x 256thr. Block = 16 vertices = 4 QUADS (4 vertices / 64 gather rows per
// iteration). B-in-registers (wave wid owns cols [wid*32,+32), 10 frags = 40 VGPR,
// zero B traffic). A double-buffered in LDS; 4 barriers total in stage1 (vs 8 in R7);
// each iteration's gather burst = 64 rows (vf bf16 256B + edge bf16 64B) issued ~2
// iterations (~2000cy) before the vmcnt(0)-at-barrier drain -> HBM miss covered.
__global__ __launch_bounds__(256) void fused_kernel(
    const unsigned short* __restrict__ vfbf,
    const int* __restrict__ aadj, const int* __restrict__ badj,
    const unsigned short* __restrict__ ebf, const float* __restrict__ nbs,
    const float* __restrict__ h0,
    const unsigned short* __restrict__ w1f, const unsigned short* __restrict__ w2f,
    const unsigned short* __restrict__ w3f,
    const float* __restrict__ b1, const float* __restrict__ b2, const float* __restrict__ b3,
    const float* __restrict__ lamda, const float* __restrict__ alpha,
    const int* __restrict__ lval,
    float* __restrict__ out)
{
  __shared__ __align__(16) unsigned short abuf[2][64 * ASTR];   // 2 x 21 KB
  __shared__ __align__(16) unsigned short nl_lds[16 * NLSTR];
  __shared__ __align__(16) unsigned short sup_lds[16 * NLSTR];
  const int wid  = threadIdx.x >> 6;
  const int lane = threadIdx.x & 63;
  const int n32  = lane & 31;
  const int h    = lane >> 5;
  const int col  = lane & 15;
  const int quad = lane >> 4;
  const int v0   = blockIdx.x * 16;

  // ---- B strip into registers (wave wid -> nc2 = wid): 10 frags = 40 VGPR ----
  FragU bw[10];
#pragma unroll
  for (int kc = 0; kc < 10; kc++)
    bw[kc].u = *(const ushort8v*)(w1f + ((wid * 10 + kc) * 64 + lane) * 8);

  const float bb1 = b1[wid * 32 + n32];
  const float4* nbs4 = (const float4*)nbs;

  // staging: 4 threads per A row; 64 rows per quad
  const int srow = threadIdx.x >> 2;   // 0..63
  const int ssub = threadIdx.x & 3;    // 0..3

  // preload adjacency for all 4 quads (coalesced)
  int a_[4], e_[4];
#pragma unroll
  for (int q = 0; q < 4; q++){
    const int fi = v0 * 16 + q * 64 + srow;
    a_[q] = aadj[fi];
    e_[q] = badj[fi];
  }

  // prefetch registers: 64B of vf row + 16B of edge row per thread
  ushort8v pv0, pv1, pv2, pv3, pe1;

#define ISSUE(q) { \
    const ushort8v* vr = (const ushort8v*)(vfbf + (size_t)a_[q] * 128) + ssub * 4; \
    pv0 = vr[0]; pv1 = vr[1]; pv2 = vr[2]; pv3 = vr[3]; \
    pe1 = *(const ushort8v*)(ebf + (size_t)e_[q] * 32 + ssub * 8); }
#define COMMIT(bsel) { \
    unsigned short* dst = abuf[bsel] + srow * ASTR + ssub * 32; \
    *(ushort8v*)(dst)      = pv0; *(ushort8v*)(dst + 8)  = pv1; \
    *(ushort8v*)(dst + 16) = pv2; *(ushort8v*)(dst + 24) = pv3; \
    *(ushort8v*)(abuf[bsel] + srow * ASTR + 128 + ssub * 8) = pe1; }

  ISSUE(0); COMMIT(0); ISSUE(1);

#pragma unroll 1
  for (int it = 0; it < 4; ++it){
    __syncthreads();                 // abuf[it&1] ready; prior reads of abuf[(it+1)&1] done
    if (it < 3) COMMIT((it + 1) & 1);      // quad it+1 (loads issued at it-1)
    if (it < 2) ISSUE(it + 2);             // quad it+2 (lands during this iteration)

    // ---- compute quad it: 2 x (32x32x16 over K=160), A from LDS, B from regs ----
#pragma unroll
    for (int m = 0; m < 2; m++){
      const unsigned short* ab = abuf[it & 1] + (m * 32 + n32) * ASTR + h * 8;
      f32x16 acc = {};
#pragma unroll
      for (int kc = 0; kc < 10; kc++){
        FragU fa;
        fa.u = *(const ushort8v*)(ab + kc * 16);
        acc = __builtin_amdgcn_mfma_f32_32x32x16_bf16(fa.b, bw[kc].b, acc, 0, 0, 0);
      }
      // epilogue: +b1, GELU, mask, reduce; C row=(reg&3)+8*(reg>>2)+4*h
      const int vA = v0 + 4 * it + 2 * m;
      const float4 mAlo = nbs4[vA * 4 + h],       mAhi = nbs4[vA * 4 + 2 + h];
      const float4 mBlo = nbs4[(vA + 1) * 4 + h], mBhi = nbs4[(vA + 1) * 4 + 2 + h];
      float sA = gelu_f(acc[0] + bb1) * mAlo.x + gelu_f(acc[1] + bb1) * mAlo.y
               + gelu_f(acc[2] + bb1) * mAlo.z + gelu_f(acc[3] + bb1) * mAlo.w
               + gelu_f(acc[4] + bb1) * mAhi.x + gelu_f(acc[5] + bb1) * mAhi.y
               + gelu_f(acc[6] + bb1) * mAhi.z + gelu_f(acc[7] + bb1) * mAhi.w;
      float sB = gelu_f(acc[8] + bb1) * mBlo.x + gelu_f(acc[9] + bb1) * mBlo.y
               + gelu_f(acc[10] + bb1) * mBlo.z + gelu_f(acc[11] + bb1) * mBlo.w
               + gelu_f(acc[12] + bb1) * mBhi.x + gelu_f(acc[13] + bb1) * mBhi.y
               + gelu_f(acc[14] + bb1) * mBhi.z + gelu_f(acc[15] + bb1) * mBhi.w;
      sA += __shfl_xor(sA, 32, 64);
      sB += __shfl_xor(sB, 32, 64);
      if (h == 0) nl_lds[(4 * it + 2 * m)     * NLSTR + wid * 32 + n32] = f2bf(sA);
      else        nl_lds[(4 * it + 2 * m + 1) * NLSTR + wid * 32 + n32] = f2bf(sB);
    }
  }
#undef ISSUE
#undef COMMIT
  __syncthreads();

  // ---------------- stage 2: wave wid computes output cols [wid*32, wid*32+32) --------
  const int nc0 = 2 * wid;
  const float th = logf(lamda[0] / (float)lval[0] + 1.0f);
  const float al = alpha[0];

  f32x4 acc2[2] = {};
#pragma unroll
  for (int kc = 0; kc < 8; kc++){
    FragU a;
    if (kc < 4) a.u = *(const ushort8v*)(nl_lds + col * NLSTR + kc * 32 + quad * 8);
    else        a.u = *(const ushort8v*)(vfbf + (size_t)(v0 + col) * 128 + (kc - 4) * 32 + quad * 8);
#pragma unroll
    for (int pq = 0; pq < 2; pq++){
      FragU bf_;
      bf_.u = *(const ushort8v*)(w2f + ((kc * 8 + nc0 + pq) * 64 + lane) * 8);
      acc2[pq] = __builtin_amdgcn_mfma_f32_16x16x32_bf16(a.b, bf_.b, acc2[pq], 0, 0, 0);
    }
  }

  float sup[2][4];
#pragma unroll
  for (int pq = 0; pq < 2; pq++){
    const int d = (nc0 + pq) * 16 + col;
    const float bb = b2[d];
#pragma unroll
    for (int r = 0; r < 4; r++){
      const int vtx = v0 + quad * 4 + r;
      float hi = acc2[pq][r] + bb;
      float s = (1.f - al) * hi + al * h0[vtx * 128 + d];
      sup[pq][r] = s;
      sup_lds[(quad * 4 + r) * NLSTR + d] = f2bf(s);
    }
  }
  __syncthreads();

  f32x4 acc3[2] = {};
#pragma unroll
  for (int kc = 0; kc < 4; kc++){
    FragU a;
    a.u = *(const ushort8v*)(sup_lds + col * NLSTR + kc * 32 + quad * 8);
#pragma unroll
    for (int pq = 0; pq < 2; pq++){
      FragU bf_;
      bf_.u = *(const ushort8v*)(w3f + ((kc * 8 + nc0 + pq) * 64 + lane) * 8);
      acc3[pq] = __builtin_amdgcn_mfma_f32_16x16x32_bf16(a.b, bf_.b, acc3[pq], 0, 0, 0);
    }
  }

#pragma unroll
  for (int pq = 0; pq < 2; pq++){
    const int d = (nc0 + pq) * 16 + col;
    const float bb = b3[d];
#pragma unroll
    for (int r = 0; r < 4; r++){
      const int vtx = v0 + quad * 4 + r;
      float res = bf2f(vfbf[(size_t)vtx * 128 + d]);
      out[vtx * 128 + d] = th * (acc3[pq][r] + bb) + (1.f - th) * sup[pq][r] + res;
    }
  }
}

extern "C" void kernel_launch(void* const* d_in, const int* in_sizes, int n_in,
                              void* d_out, int out_size, void* d_ws, size_t ws_size,
                              hipStream_t stream)
{
  const float* vfp  = (const float*)d_in[0];
  const int*   aadj = (const int*)d_in[1];
  const int*   badj = (const int*)d_in[2];
  const float* h0   = (const float*)d_in[3];
  const float* lam  = (const float*)d_in[4];
  const float* alp  = (const float*)d_in[5];
  const int*   lv   = (const int*)d_in[6];
  const float* edge = (const float*)d_in[7];
  // d_in[8] vertex_mask: unused by the reference math
  const float* nbs  = (const float*)d_in[9];
  const float* W1   = (const float*)d_in[10];
  const float* b1   = (const float*)d_in[11];
  const float* W2   = (const float*)d_in[12];
  const float* b2   = (const float*)d_in[13];
  const float* W3   = (const float*)d_in[14];
  const float* b3   = (const float*)d_in[15];
  float* out = (float*)d_out;

  // ws layout (ushorts): w1f [0,20480) | w2f [20480,53248) | w3f [53248,69632)
  //   | vfbf [69632, 2166784) | ebf [2166784, 10555392)  -> ~21.1 MB total
  unsigned short* w1f  = (unsigned short*)d_ws;
  unsigned short* w2f  = w1f + 20480;
  unsigned short* w3f  = w2f + 32768;
  unsigned short* vfbf = w3f + 16384;
  unsigned short* ebf  = vfbf + 2097152;

  prep_kernel<<<5154, 256, 0, stream>>>(vfp, edge, W1, W2, W3, vfbf, ebf, w1f, w2f, w3f);
  fused_kernel<<<1024, 256, 0, stream>>>(vfbf, aadj, badj, ebf, nbs, h0,
                                         w1f, w2f, w3f, b1, b2, b3, lam, alp, lv, out);
}

// Round 11
// 146.053 us; speedup vs baseline: 1.1392x; 1.0009x over previous
//
#include <hip/hip_runtime.h>
#include <hip/hip_bf16.h>
#include <math.h>

// Problem constants: B=32 V=512 K=16 D=128 E=32 NE=8192 -> BV=16384 vertices
#define NLSTR 136   // LDS row stride (ushorts) for 16x128 tiles
#define ASTR  168   // LDS row stride (ushorts) for A rows: 160 + 8 pad (336B, 16B-aligned)

typedef __bf16 bf16x8 __attribute__((ext_vector_type(8)));
typedef float f32x4 __attribute__((ext_vector_type(4)));
typedef float f32x16 __attribute__((ext_vector_type(16)));
typedef unsigned short ushort8v __attribute__((ext_vector_type(8)));

union FragU { ushort8v u; bf16x8 b; };

static __device__ inline unsigned short f2bf(float f){
  unsigned u = __float_as_uint(f);
  u += 0x7fffu + ((u >> 16) & 1u);   // RNE
  return (unsigned short)(u >> 16);
}
static __device__ inline float bf2f(unsigned short u){
  return __uint_as_float(((unsigned)u) << 16);
}
static __device__ inline unsigned pk2(float a, float b){
  union { __hip_bfloat162 h; unsigned u; } r;
  r.h = __float22bfloat162_rn(float2{a, b});
  return r.u;
}
static __device__ inline ushort8v pkcvt8(float4 a, float4 b){
  union { unsigned u[4]; ushort8v v; } r;
  r.u[0] = pk2(a.x, a.y); r.u[1] = pk2(a.z, a.w);
  r.u[2] = pk2(b.x, b.y); r.u[3] = pk2(b.z, b.w);
  return r.v;
}

// tanh-form GELU (max err ~3e-4 vs exact erf-GELU)
static __device__ inline float gelu_f(float x){
  float u = x * x;
  float p = fmaf(u, 0.07135481283f, 1.5957691216f);
  float t = x * p;
  float e = __builtin_amdgcn_exp2f(t * -1.44269504f);
  return x * __builtin_amdgcn_rcpf(1.0f + e);
}

// ---------------- prep ----------------
// egath: PRE-GATHERED bf16 edge rows in adjacency order: egath[fi] = bf16(edge[badj[fi]])
//   -> fused reads edges fully sequentially (the random gather happens HERE, in a
//      barrier-free streaming kernel with 32K independent waves: latency trivially hidden).
// vfbf: bf16 vertex table (4 MB, L2-resident gather target for fused).
// w1f: 32x32x16 B-frags, strip-major (nc2*10+kc);  w2f/w3f: 16x16x32 B-frags (kc*8+nc).
__global__ __launch_bounds__(256) void prep_kernel(
    const float* __restrict__ vf, const float* __restrict__ edge,
    const int* __restrict__ badj,
    const float* __restrict__ W1, const float* __restrict__ W2, const float* __restrict__ W3,
    unsigned short* __restrict__ vfbf, unsigned short* __restrict__ egath,
    unsigned short* __restrict__ w1f, unsigned short* __restrict__ w2f,
    unsigned short* __restrict__ w3f)
{
  int t = blockIdx.x * 256 + threadIdx.x;
  if (t < 1048576){                      // edge gather+cvt: 262144 rows x 4 threads
    const int fi = t >> 2, sub = t & 3;
    const int e = badj[fi];
    const float4* er = (const float4*)(edge + (size_t)e * 32 + sub * 8);
    float4 x = er[0], y = er[1];
    *(ushort8v*)(egath + (size_t)fi * 32 + sub * 8) = pkcvt8(x, y);
    return;
  }
  t -= 1048576;
  if (t < 262144){                       // vfbf: 16384*128 / 8
    const float4* src = (const float4*)vf;
    float4 x = src[t * 2], y = src[t * 2 + 1];
    *(ushort8v*)(vfbf + (size_t)t * 8) = pkcvt8(x, y);
    return;
  }
  int t2 = t - 262144;
  const float* s;
  unsigned short* d;
  if (t2 < 2560){                        // w1f: 4nc2 x 10kc strip-major (32x32x16)
    int fragid = t2 >> 6, lane = t2 & 63;
    int nc2 = fragid / 10, kc = fragid % 10, n = lane & 31, h = lane >> 5;
    s = W1 + (nc2 * 32 + n) * 160 + kc * 16 + h * 8;
    d = w1f + t2 * 8;
  } else if (t2 < 6656){                 // w2f: 8kc x 8nc
    int t3 = t2 - 2560;
    int fragid = t3 >> 6, lane = t3 & 63;
    int kc = fragid >> 3, nc = fragid & 7, col = lane & 15, quad = lane >> 4;
    s = W2 + (nc * 16 + col) * 256 + kc * 32 + quad * 8;
    d = w2f + t3 * 8;
  } else if (t2 < 8704){                 // w3f: 4kc x 8nc
    int t3 = t2 - 6656;
    int fragid = t3 >> 6, lane = t3 & 63;
    int kc = fragid >> 3, nc = fragid & 7, col = lane & 15, quad = lane >> 4;
    s = W3 + (nc * 16 + col) * 128 + kc * 32 + quad * 8;
    d = w3f + t3 * 8;
  } else return;
#pragma unroll
  for (int j = 0; j < 8; j++) d[j] = f2bf(s[j]);
}

// ---------------- fused ----------------
// grid 1024 x 256thr. Block = 16 vertices = 4 QUADS (4 vertices / 64 A-rows per
// iteration). B-in-registers (wave wid owns cols [wid*32,+32), 10 frags = 40 VGPR,
// zero B traffic). A double-buffered in LDS (4 stage1 barriers). Edge part of A is
// read SEQUENTIALLY from egath (4 KB contiguous per quad) -- no random edge gather
// in this kernel; only the L2-resident vfbf table is gathered (~200cy, covered by
// the 2-iteration prefetch distance).
__global__ __launch_bounds__(256) void fused_kernel(
    const unsigned short* __restrict__ vfbf,
    const int* __restrict__ aadj,
    const unsigned short* __restrict__ egath, const float* __restrict__ nbs,
    const float* __restrict__ h0,
    const unsigned short* __restrict__ w1f, const unsigned short* __restrict__ w2f,
    const unsigned short* __restrict__ w3f,
    const float* __restrict__ b1, const float* __restrict__ b2, const float* __restrict__ b3,
    const float* __restrict__ lamda, const float* __restrict__ alpha,
    const int* __restrict__ lval,
    float* __restrict__ out)
{
  __shared__ __align__(16) unsigned short abuf[2][64 * ASTR];   // 2 x 21 KB
  __shared__ __align__(16) unsigned short nl_lds[16 * NLSTR];
  __shared__ __align__(16) unsigned short sup_lds[16 * NLSTR];
  const int wid  = threadIdx.x >> 6;
  const int lane = threadIdx.x & 63;
  const int n32  = lane & 31;
  const int h    = lane >> 5;
  const int col  = lane & 15;
  const int quad = lane >> 4;
  const int v0   = blockIdx.x * 16;

  // ---- B strip into registers (wave wid -> nc2 = wid): 10 frags = 40 VGPR ----
  FragU bw[10];
#pragma unroll
  for (int kc = 0; kc < 10; kc++)
    bw[kc].u = *(const ushort8v*)(w1f + ((wid * 10 + kc) * 64 + lane) * 8);

  const float bb1 = b1[wid * 32 + n32];
  const float4* nbs4 = (const float4*)nbs;

  // staging: 4 threads per A row; 64 rows per quad
  const int srow = threadIdx.x >> 2;   // 0..63
  const int ssub = threadIdx.x & 3;    // 0..3

  // preload vertex-gather adjacency for all 4 quads (coalesced; edge adj not needed)
  int a_[4];
#pragma unroll
  for (int q = 0; q < 4; q++)
    a_[q] = aadj[v0 * 16 + q * 64 + srow];

  // prefetch registers: 64B of vf row (gather) + 16B of edge row (sequential)
  ushort8v pv0, pv1, pv2, pv3, pe1;

#define ISSUE(q) { \
    const ushort8v* vr = (const ushort8v*)(vfbf + (size_t)a_[q] * 128) + ssub * 4; \
    pv0 = vr[0]; pv1 = vr[1]; pv2 = vr[2]; pv3 = vr[3]; \
    pe1 = *(const ushort8v*)(egath + ((size_t)(v0 * 16 + (q) * 64 + srow)) * 32 + ssub * 8); }
#define COMMIT(bsel) { \
    unsigned short* dst = abuf[bsel] + srow * ASTR + ssub * 32; \
    *(ushort8v*)(dst)      = pv0; *(ushort8v*)(dst + 8)  = pv1; \
    *(ushort8v*)(dst + 16) = pv2; *(ushort8v*)(dst + 24) = pv3; \
    *(ushort8v*)(abuf[bsel] + srow * ASTR + 128 + ssub * 8) = pe1; }

  ISSUE(0); COMMIT(0); ISSUE(1);

#pragma unroll 1
  for (int it = 0; it < 4; ++it){
    __syncthreads();                 // abuf[it&1] ready; prior reads of abuf[(it+1)&1] done
    if (it < 3) COMMIT((it + 1) & 1);      // quad it+1 (loads issued at it-1)
    if (it < 2) ISSUE(it + 2);             // quad it+2 (lands during this iteration)

    // ---- compute quad it: 2 x (32x32x16 over K=160), A from LDS, B from regs ----
#pragma unroll
    for (int m = 0; m < 2; m++){
      const unsigned short* ab = abuf[it & 1] + (m * 32 + n32) * ASTR + h * 8;
      f32x16 acc = {};
#pragma unroll
      for (int kc = 0; kc < 10; kc++){
        FragU fa;
        fa.u = *(const ushort8v*)(ab + kc * 16);
        acc = __builtin_amdgcn_mfma_f32_32x32x16_bf16(fa.b, bw[kc].b, acc, 0, 0, 0);
      }
      // epilogue: +b1, GELU, mask, reduce; C row=(reg&3)+8*(reg>>2)+4*h
      const int vA = v0 + 4 * it + 2 * m;
      const float4 mAlo = nbs4[vA * 4 + h],       mAhi = nbs4[vA * 4 + 2 + h];
      const float4 mBlo = nbs4[(vA + 1) * 4 + h], mBhi = nbs4[(vA + 1) * 4 + 2 + h];
      float sA = gelu_f(acc[0] + bb1) * mAlo.x + gelu_f(acc[1] + bb1) * mAlo.y
               + gelu_f(acc[2] + bb1) * mAlo.z + gelu_f(acc[3] + bb1) * mAlo.w
               + gelu_f(acc[4] + bb1) * mAhi.x + gelu_f(acc[5] + bb1) * mAhi.y
               + gelu_f(acc[6] + bb1) * mAhi.z + gelu_f(acc[7] + bb1) * mAhi.w;
      float sB = gelu_f(acc[8] + bb1) * mBlo.x + gelu_f(acc[9] + bb1) * mBlo.y
               + gelu_f(acc[10] + bb1) * mBlo.z + gelu_f(acc[11] + bb1) * mBlo.w
               + gelu_f(acc[12] + bb1) * mBhi.x + gelu_f(acc[13] + bb1) * mBhi.y
               + gelu_f(acc[14] + bb1) * mBhi.z + gelu_f(acc[15] + bb1) * mBhi.w;
      sA += __shfl_xor(sA, 32, 64);
      sB += __shfl_xor(sB, 32, 64);
      if (h == 0) nl_lds[(4 * it + 2 * m)     * NLSTR + wid * 32 + n32] = f2bf(sA);
      else        nl_lds[(4 * it + 2 * m + 1) * NLSTR + wid * 32 + n32] = f2bf(sB);
    }
  }
#undef ISSUE
#undef COMMIT
  __syncthreads();

  // ---------------- stage 2: wave wid computes output cols [wid*32, wid*32+32) --------
  const int nc0 = 2 * wid;
  const float th = logf(lamda[0] / (float)lval[0] + 1.0f);
  const float al = alpha[0];

  f32x4 acc2[2] = {};
#pragma unroll
  for (int kc = 0; kc < 8; kc++){
    FragU a;
    if (kc < 4) a.u = *(const ushort8v*)(nl_lds + col * NLSTR + kc * 32 + quad * 8);
    else        a.u = *(const ushort8v*)(vfbf + (size_t)(v0 + col) * 128 + (kc - 4) * 32 + quad * 8);
#pragma unroll
    for (int pq = 0; pq < 2; pq++){
      FragU bf_;
      bf_.u = *(const ushort8v*)(w2f + ((kc * 8 + nc0 + pq) * 64 + lane) * 8);
      acc2[pq] = __builtin_amdgcn_mfma_f32_16x16x32_bf16(a.b, bf_.b, acc2[pq], 0, 0, 0);
    }
  }

  float sup[2][4];
#pragma unroll
  for (int pq = 0; pq < 2; pq++){
    const int d = (nc0 + pq) * 16 + col;
    const float bb = b2[d];
#pragma unroll
    for (int r = 0; r < 4; r++){
      const int vtx = v0 + quad * 4 + r;
      float hi = acc2[pq][r] + bb;
      float s = (1.f - al) * hi + al * h0[vtx * 128 + d];
      sup[pq][r] = s;
      sup_lds[(quad * 4 + r) * NLSTR + d] = f2bf(s);
    }
  }
  __syncthreads();

  f32x4 acc3[2] = {};
#pragma unroll
  for (int kc = 0; kc < 4; kc++){
    FragU a;
    a.u = *(const ushort8v*)(sup_lds + col * NLSTR + kc * 32 + quad * 8);
#pragma unroll
    for (int pq = 0; pq < 2; pq++){
      FragU bf_;
      bf_.u = *(const ushort8v*)(w3f + ((kc * 8 + nc0 + pq) * 64 + lane) * 8);
      acc3[pq] = __builtin_amdgcn_mfma_f32_16x16x32_bf16(a.b, bf_.b, acc3[pq], 0, 0, 0);
    }
  }

#pragma unroll
  for (int pq = 0; pq < 2; pq++){
    const int d = (nc0 + pq) * 16 + col;
    const float bb = b3[d];
#pragma unroll
    for (int r = 0; r < 4; r++){
      const int vtx = v0 + quad * 4 + r;
      float res = bf2f(vfbf[(size_t)vtx * 128 + d]);
      out[vtx * 128 + d] = th * (acc3[pq][r] + bb) + (1.f - th) * sup[pq][r] + res;
    }
  }
}

extern "C" void kernel_launch(void* const* d_in, const int* in_sizes, int n_in,
                              void* d_out, int out_size, void* d_ws, size_t ws_size,
                              hipStream_t stream)
{
  const float* vfp  = (const float*)d_in[0];
  const int*   aadj = (const int*)d_in[1];
  const int*   badj = (const int*)d_in[2];
  const float* h0   = (const float*)d_in[3];
  const float* lam  = (const float*)d_in[4];
  const float* alp  = (const float*)d_in[5];
  const int*   lv   = (const int*)d_in[6];
  const float* edge = (const float*)d_in[7];
  // d_in[8] vertex_mask: unused by the reference math
  const float* nbs  = (const float*)d_in[9];
  const float* W1   = (const float*)d_in[10];
  const float* b1   = (const float*)d_in[11];
  const float* W2   = (const float*)d_in[12];
  const float* b2   = (const float*)d_in[13];
  const float* W3   = (const float*)d_in[14];
  const float* b3   = (const float*)d_in[15];
  float* out = (float*)d_out;

  // ws layout (ushorts): w1f [0,20480) | w2f [20480,53248) | w3f [53248,69632)
  //   | vfbf [69632, 2166784) | egath [2166784, 10555392)  -> ~21.1 MB total
  unsigned short* w1f   = (unsigned short*)d_ws;
  unsigned short* w2f   = w1f + 20480;
  unsigned short* w3f   = w2f + 32768;
  unsigned short* vfbf  = w3f + 16384;
  unsigned short* egath = vfbf + 2097152;

  prep_kernel<<<5154, 256, 0, stream>>>(vfp, edge, badj, W1, W2, W3,
                                        vfbf, egath, w1f, w2f, w3f);
  fused_kernel<<<1024, 256, 0, stream>>>(vfbf, aadj, egath, nbs, h0,
                                         w1f, w2f, w3f, b1, b2, b3, lam, alp, lv, out);
}